// Round 1
// 520.121 us; speedup vs baseline: 1.0459x; 1.0459x over previous
//
#include <hip/hip_runtime.h>
#include <hip/hip_bf16.h>
#include <math.h>

#define NN 100000
#define CC 128
#define EE 1600000
#define SCAN_CHUNK 2048
#define NB_SCAN ((NN + SCAN_CHUNK - 1) / SCAN_CHUNK)  // 49
#define NRANGE 8
#define RNODES (NN / NRANGE)     // 12500
#define EPT 8                    // edges per thread in partitioned edge kernels
#define FCHUNK (256 * EPT)       // 2048 edges per block
#define NCHUNKS ((EE + FCHUNK - 1) / FCHUNK)  // 782

typedef short  bf16x8 __attribute__((ext_vector_type(8)));
typedef float  f32x4  __attribute__((ext_vector_type(4)));
typedef float  f32x4v __attribute__((ext_vector_type(4)));
typedef unsigned short u16x8 __attribute__((ext_vector_type(8)));

#define WPAD 136   // ushort stride for LDS weight rows (272 B -> 2-way bank alias, free)
#define TPAD 132   // float stride for per-wave T tiles (528 B)
#define MLPB 256   // persistent MLP blocks (1 per CU)
#define MLPW 8     // waves per MLP block (512 thr): 2 waves/SIMD at 1 block/CU

__device__ __forceinline__ ushort f2bf(float f) {
    __hip_bfloat16 h = __float2bfloat16(f);   // RNE
    return __builtin_bit_cast(ushort, h);
}
__device__ __forceinline__ float bf2f(ushort u) {
    return __builtin_bit_cast(float, ((unsigned int)u) << 16);
}

// ===========================================================================
// CSR build. hist_part keeps the R7 measured-best partitioned atomic form but
// now captures the atomic's RETURN VALUE as the edge's within-node rank
// (rank[] aliases the agg buffer, dead until the first gather). fill then
// needs NO atomics and NO 8x dst re-read: col[rowptr[d]+rank[e]] = src[e].
// ===========================================================================
__global__ void __launch_bounds__(256) hist_part(
    const int* __restrict__ dst, int* __restrict__ deg, int* __restrict__ rank)
{
    int range = blockIdx.x & (NRANGE - 1);
    int chunk = blockIdx.x >> 3;
    int lo = range * RNODES, hi = lo + RNODES;
    int base = chunk * FCHUNK + threadIdx.x * EPT;
    if (base + EPT <= EE) {
        int4 d0 = *(const int4*)&dst[base];
        int4 d1 = *(const int4*)&dst[base + 4];
        int dd[8] = {d0.x, d0.y, d0.z, d0.w, d1.x, d1.y, d1.z, d1.w};
#pragma unroll
        for (int i = 0; i < 8; ++i) {
            int d = dd[i];
            if (d >= lo && d < hi) {
                int r = atomicAdd(&deg[d], 1);
                rank[base + i] = r;
            }
        }
    } else {
        for (int i = 0; i < EPT; ++i) {
            int e = base + i;
            if (e < EE) {
                int d = dst[e];
                if (d >= lo && d < hi) {
                    int r = atomicAdd(&deg[d], 1);
                    rank[e] = r;
                }
            }
        }
    }
}

__global__ void __launch_bounds__(256) deg_block_reduce(
    const int* __restrict__ deg, int* __restrict__ blockSums)
{
    int base = blockIdx.x * SCAN_CHUNK + threadIdx.x * 8;
    int s = 0;
#pragma unroll
    for (int i = 0; i < 8; ++i) {
        int idx = base + i;
        if (idx < NN) s += deg[idx];
    }
#pragma unroll
    for (int off = 32; off > 0; off >>= 1) s += __shfl_down(s, off);
    __shared__ int ws[4];
    int lane = threadIdx.x & 63, wid = threadIdx.x >> 6;
    if (lane == 0) ws[wid] = s;
    __syncthreads();
    if (threadIdx.x == 0) blockSums[blockIdx.x] = ws[0] + ws[1] + ws[2] + ws[3];
}

__global__ void scan_offsets(const int* __restrict__ blockSums,
                             int* __restrict__ blockOff, int* __restrict__ rowptr)
{
    int lane = threadIdx.x;  // 64 threads
    int v = (lane < NB_SCAN) ? blockSums[lane] : 0;
    int inc = v;
#pragma unroll
    for (int off = 1; off < 64; off <<= 1) {
        int n = __shfl_up(inc, off);
        if (lane >= off) inc += n;
    }
    if (lane < NB_SCAN) blockOff[lane] = inc - v;
    if (lane == 63) rowptr[NN] = EE;
}

__global__ void __launch_bounds__(256) deg_scan_write(
    const int* __restrict__ deg, const int* __restrict__ blockOff,
    int* __restrict__ rowptr)
{
    __shared__ int warpSums[4];
    int base = blockIdx.x * SCAN_CHUNK + threadIdx.x * 8;
    int v[8];
    int s = 0;
#pragma unroll
    for (int i = 0; i < 8; ++i) {
        int idx = base + i;
        v[i] = (idx < NN) ? deg[idx] : 0;
        s += v[i];
    }
    int lane = threadIdx.x & 63, wid = threadIdx.x >> 6;
    int inc = s;
#pragma unroll
    for (int off = 1; off < 64; off <<= 1) {
        int n = __shfl_up(inc, off);
        if (lane >= off) inc += n;
    }
    if (lane == 63) warpSums[wid] = inc;
    __syncthreads();
    int wofs = 0;
#pragma unroll
    for (int w = 0; w < 4; ++w)
        if (w < wid) wofs += warpSums[w];
    int exc = blockOff[blockIdx.x] + wofs + (inc - s);
#pragma unroll
    for (int i = 0; i < 8; ++i) {
        int idx = base + i;
        if (idx < NN) rowptr[idx] = exc;
        exc += v[i];
    }
}

// Atomic-free single-pass fill: streams dst/src/rank once (19.2 MB total),
// rowptr gathers are L2-resident (400 KB), scatter-stores col.
__global__ void __launch_bounds__(256) fill_csr_rank(
    const int* __restrict__ src, const int* __restrict__ dst,
    const int* __restrict__ rank, const int* __restrict__ rowptr,
    int* __restrict__ col)
{
    int base = blockIdx.x * FCHUNK + threadIdx.x * EPT;
    if (base + EPT <= EE) {
        int4 d0 = *(const int4*)&dst[base];
        int4 d1 = *(const int4*)&dst[base + 4];
        int4 s0 = *(const int4*)&src[base];
        int4 s1 = *(const int4*)&src[base + 4];
        int4 r0 = *(const int4*)&rank[base];
        int4 r1 = *(const int4*)&rank[base + 4];
        int dd[8] = {d0.x, d0.y, d0.z, d0.w, d1.x, d1.y, d1.z, d1.w};
        int ss[8] = {s0.x, s0.y, s0.z, s0.w, s1.x, s1.y, s1.z, s1.w};
        int rr[8] = {r0.x, r0.y, r0.z, r0.w, r1.x, r1.y, r1.z, r1.w};
#pragma unroll
        for (int i = 0; i < 8; ++i) {
            col[rowptr[dd[i]] + rr[i]] = ss[i];
        }
    } else {
        for (int i = 0; i < EPT; ++i) {
            int e = base + i;
            if (e < EE) {
                col[rowptr[dst[e]] + rank[e]] = src[e];
            }
        }
    }
}

// ===========================================================================
// Conversions (convert_x also zeroes deg -> one fewer dispatch)
// ===========================================================================
__global__ void __launch_bounds__(256) convert_x_kernel(
    const float* __restrict__ x, ushort* __restrict__ xb, int* __restrict__ deg)
{
    int i = blockIdx.x * 256 + threadIdx.x;   // float4 groups; NN*CC/4 total
    f32x4v v = __builtin_nontemporal_load((const f32x4v*)x + i);  // single-use stream
    ushort4 o;
    o.x = f2bf(v[0]); o.y = f2bf(v[1]); o.z = f2bf(v[2]); o.w = f2bf(v[3]);
    ((ushort4*)xb)[i] = o;
    if (i < NN) deg[i] = 0;
}

__global__ void __launch_bounds__(256) convert_w6_kernel(
    const float* __restrict__ w0, const float* __restrict__ w1,
    const float* __restrict__ w2, const float* __restrict__ w3,
    const float* __restrict__ w4, const float* __restrict__ w5,
    ushort* __restrict__ wt)
{
    int i = blockIdx.x * 256 + threadIdx.x;  // 6*16384
    int mat = i >> 14;
    int rem = i & 16383;
    int k = rem >> 7, n = rem & 127;
    const float* w = (mat == 0) ? w0 : (mat == 1) ? w1 : (mat == 2) ? w2
                   : (mat == 3) ? w3 : (mat == 4) ? w4 : w5;
    wt[mat * 16384 + n * 128 + k] = f2bf(w[k * 128 + n]);
}

// ===========================================================================
// Standalone max-occupancy gather: agg[n] = h[n] + sum_nbr h[nbr]  (bf16)
// At the random-graph L2-miss floor (~67 us/layer).
// ===========================================================================
__global__ void __launch_bounds__(256) gather_agg(
    const ushort* __restrict__ hin, const int* __restrict__ rowptr,
    const int* __restrict__ col, ushort* __restrict__ agg)
{
    const int grp    = threadIdx.x >> 4;            // 0..15
    const int lane16 = threadIdx.x & 15;
    const int gbase  = (threadIdx.x & 63) & 48;     // group base lane in wave
    const int n = blockIdx.x * 16 + grp;            // 6250*16 = 100000 exact
    const u16x8* hp = (const u16x8*)hin;

    u16x8 self = hp[n * 16 + lane16];
    float s0[8], s1[8], s2[8], s3[8];
#pragma unroll
    for (int k = 0; k < 8; ++k) {
        s0[k] = bf2f(self[k]); s1[k] = 0.f; s2[k] = 0.f; s3[k] = 0.f;
    }

    int beg = rowptr[n], end = rowptr[n + 1];
    while (beg < end) {
        int take = end - beg;
        if (take > 16) take = 16;
        int ci = (lane16 < take) ? col[beg + lane16] : 0;
        int j = 0;
        for (; j + 4 <= take; j += 4) {
            int n0 = __shfl(ci, gbase + j + 0);
            int n1 = __shfl(ci, gbase + j + 1);
            int n2 = __shfl(ci, gbase + j + 2);
            int n3 = __shfl(ci, gbase + j + 3);
            u16x8 a0 = hp[n0 * 16 + lane16];
            u16x8 a1 = hp[n1 * 16 + lane16];
            u16x8 a2 = hp[n2 * 16 + lane16];
            u16x8 a3 = hp[n3 * 16 + lane16];
#pragma unroll
            for (int k = 0; k < 8; ++k) {
                s0[k] += bf2f(a0[k]); s1[k] += bf2f(a1[k]);
                s2[k] += bf2f(a2[k]); s3[k] += bf2f(a3[k]);
            }
        }
        for (; j < take; ++j) {
            int n0 = __shfl(ci, gbase + j);
            u16x8 a0 = hp[n0 * 16 + lane16];
#pragma unroll
            for (int k = 0; k < 8; ++k) s0[k] += bf2f(a0[k]);
        }
        beg += take;
    }

    bf16x8 o;
#pragma unroll
    for (int k = 0; k < 8; ++k) o[k] = (short)f2bf(s0[k] + s1[k] + s2[k] + s3[k]);
    *(bf16x8*)&((ushort*)agg)[n * CC + lane16 * 8] = o;
}

// ===========================================================================
// Persistent weights-in-LDS MFMA MLP: 256 blocks (1/CU), now 8 waves/block
// (512 thr) -> 2 waves/SIMD instead of 1: the kernel was latency-bound at
// 1 wave/SIMD (every ds_read / T round-trip / expm1f chain serially exposed).
// Per-wave logic unchanged. LDS: 2*34816 (weights) + 8*8448 (T) = 137216 B.
// ===========================================================================
template <bool FUSE_HEAD>
__global__ void __launch_bounds__(512, 2) mlp_persist(
    const ushort* __restrict__ hin,
    const ushort* __restrict__ waT, const float* __restrict__ ba,
    const ushort* __restrict__ wbT, const float* __restrict__ bb,
    ushort* __restrict__ hout,
    const float* __restrict__ lw, const float* __restrict__ lb,
    float* __restrict__ out)
{
    __shared__ ushort WaS[CC * WPAD];      // [n][k], row stride 136
    __shared__ ushort WbS[CC * WPAD];
    __shared__ float  Tt[MLPW][16 * TPAD]; // per-wave private T

    const int tid = threadIdx.x;

    // ---- cooperative weight staging (coalesced 16B chunks) ----
    for (int i = tid; i < CC * 16; i += 512) {         // 2048 chunks per matrix
        int row = i >> 4, ch = i & 15;
        *(bf16x8*)&WaS[row * WPAD + ch * 8] = *(const bf16x8*)&waT[row * CC + ch * 8];
        *(bf16x8*)&WbS[row * WPAD + ch * 8] = *(const bf16x8*)&wbT[row * CC + ch * 8];
    }
    __syncthreads();

    const int wave = tid >> 6;
    const int lane = tid & 63;
    const int quad = lane >> 4;
    const int l16  = lane & 15;
    float* T = Tt[wave];
    const int nTiles = NN / 16;            // 6250
    const int stride = MLPB * MLPW;        // 2048

    int wv = blockIdx.x * MLPW + wave;
    if (wv >= nTiles) return;

    // prefetch first tile's A fragments
    bf16x8 af[4];
#pragma unroll
    for (int kk = 0; kk < 4; ++kk)
        af[kk] = *(const bf16x8*)&hin[(wv * 16 + l16) * CC + kk * 32 + quad * 8];

    while (true) {
        const int wrow0 = wv * 16;
        const int wnext = wv + stride;

        // prefetch next tile's A fragments (independent of current compute)
        bf16x8 afn[4];
        if (wnext < nTiles) {
#pragma unroll
            for (int kk = 0; kk < 4; ++kk)
                afn[kk] = *(const bf16x8*)&hin[(wnext * 16 + l16) * CC + kk * 32 + quad * 8];
        }

        // ---- stage 1: T = relu(A @ Wa + ba), B from LDS ----
        f32x4 acc[8];
#pragma unroll
        for (int nt = 0; nt < 8; ++nt) acc[nt] = (f32x4){0.f, 0.f, 0.f, 0.f};
#pragma unroll
        for (int kk = 0; kk < 4; ++kk) {
#pragma unroll
            for (int nt = 0; nt < 8; ++nt) {
                bf16x8 bfrag = *(const bf16x8*)&WaS[(nt * 16 + l16) * WPAD + kk * 32 + quad * 8];
                acc[nt] = __builtin_amdgcn_mfma_f32_16x16x32_bf16(af[kk], bfrag, acc[nt], 0, 0, 0);
            }
        }
#pragma unroll
        for (int nt = 0; nt < 8; ++nt) {
            int colc = nt * 16 + l16;
            float bias = ba[colc];
#pragma unroll
            for (int r = 0; r < 4; ++r) {
                float v = acc[nt][r] + bias;
                T[(quad * 4 + r) * TPAD + colc] = fmaxf(v, 0.f);
            }
        }
        // within-wave LDS write->read: compiler lgkmcnt, no barrier

        // ---- stage-2 A fragments from T (cvt fp32 -> bf16) ----
        bf16x8 a2[4];
#pragma unroll
        for (int kk = 0; kk < 4; ++kk) {
            const float* tp = &T[l16 * TPAD + kk * 32 + quad * 8];
            float4 t0 = *(const float4*)tp;
            float4 t1 = *(const float4*)(tp + 4);
            bf16x8 f;
            f[0] = (short)f2bf(t0.x); f[1] = (short)f2bf(t0.y);
            f[2] = (short)f2bf(t0.z); f[3] = (short)f2bf(t0.w);
            f[4] = (short)f2bf(t1.x); f[5] = (short)f2bf(t1.y);
            f[6] = (short)f2bf(t1.z); f[7] = (short)f2bf(t1.w);
            a2[kk] = f;
        }

        // ---- stage 2: out = elu(T @ Wb + bb), B from LDS ----
        f32x4 acc2[8];
#pragma unroll
        for (int nt = 0; nt < 8; ++nt) acc2[nt] = (f32x4){0.f, 0.f, 0.f, 0.f};
#pragma unroll
        for (int kk = 0; kk < 4; ++kk) {
#pragma unroll
            for (int nt = 0; nt < 8; ++nt) {
                bf16x8 bfrag = *(const bf16x8*)&WbS[(nt * 16 + l16) * WPAD + kk * 32 + quad * 8];
                acc2[nt] = __builtin_amdgcn_mfma_f32_16x16x32_bf16(a2[kk], bfrag, acc2[nt], 0, 0, 0);
            }
        }

        if (FUSE_HEAD) {
            float part[4] = {0.f, 0.f, 0.f, 0.f};
#pragma unroll
            for (int nt = 0; nt < 8; ++nt) {
                int colc = nt * 16 + l16;
                float bias = bb[colc];
                float w = lw[colc];
#pragma unroll
                for (int r = 0; r < 4; ++r) {
                    float v = acc2[nt][r] + bias;
                    v = v > 0.f ? v : expm1f(v);
                    part[r] += v * w;
                }
            }
#pragma unroll
            for (int r = 0; r < 4; ++r) {
#pragma unroll
                for (int off = 8; off > 0; off >>= 1)
                    part[r] += __shfl_xor(part[r], off);
            }
            if (l16 == 0) {
                float lbv = lb[0];
#pragma unroll
                for (int r = 0; r < 4; ++r) {
                    int grow = wrow0 + quad * 4 + r;
                    float z = part[r] + lbv;
                    out[grow] = 1.f / (1.f + expf(-z));
                }
            }
        } else {
            // elu -> T (safe: same-wave a2 reads returned) -> coalesced bf16 store
#pragma unroll
            for (int nt = 0; nt < 8; ++nt) {
                int colc = nt * 16 + l16;
                float bias = bb[colc];
#pragma unroll
                for (int r = 0; r < 4; ++r) {
                    float v = acc2[nt][r] + bias;
                    T[(quad * 4 + r) * TPAD + colc] = v > 0.f ? v : expm1f(v);
                }
            }
#pragma unroll
            for (int i = 0; i < 4; ++i) {
                int r  = i * 4 + quad;           // 0..15
                int cv = l16;                    // 16B chunk (8 values)
                const float* tp = &T[r * TPAD + cv * 8];
                float4 t0 = *(const float4*)tp;
                float4 t1 = *(const float4*)(tp + 4);
                ushort4 o0, o1;
                o0.x = f2bf(t0.x); o0.y = f2bf(t0.y); o0.z = f2bf(t0.z); o0.w = f2bf(t0.w);
                o1.x = f2bf(t1.x); o1.y = f2bf(t1.y); o1.z = f2bf(t1.z); o1.w = f2bf(t1.w);
                ushort* dstp = &hout[(wrow0 + r) * CC + cv * 8];
                *(ushort4*)dstp = o0;
                *(ushort4*)(dstp + 4) = o1;
            }
        }

        if (wnext >= nTiles) break;
        wv = wnext;
#pragma unroll
        for (int kk = 0; kk < 4; ++kk) af[kk] = afn[kk];
    }
}

extern "C" void kernel_launch(void* const* d_in, const int* in_sizes, int n_in,
                              void* d_out, int out_size, void* d_ws, size_t ws_size,
                              hipStream_t stream) {
    const float* x   = (const float*)d_in[0];
    const int*   ei  = (const int*)d_in[1];
    const int*   src = ei;
    const int*   dst = ei + EE;
    const float* w0a = (const float*)d_in[2];
    const float* b0a = (const float*)d_in[3];
    const float* w0b = (const float*)d_in[4];
    const float* b0b = (const float*)d_in[5];
    const float* w1a = (const float*)d_in[6];
    const float* b1a = (const float*)d_in[7];
    const float* w1b = (const float*)d_in[8];
    const float* b1b = (const float*)d_in[9];
    const float* w2a = (const float*)d_in[10];
    const float* b2a = (const float*)d_in[11];
    const float* w2b = (const float*)d_in[12];
    const float* b2b = (const float*)d_in[13];
    const float* lw  = (const float*)d_in[14];
    const float* lb  = (const float*)d_in[15];
    float* outp = (float*)d_out;

    // workspace layout (xb reused as layer-2 output)
    ushort* xb  = (ushort*)d_ws;                      // N*CC bf16
    ushort* hbA = xb + (size_t)NN * CC;               // N*CC bf16
    ushort* agg = hbA + (size_t)NN * CC;              // N*CC bf16
    ushort* wT  = agg + (size_t)NN * CC;              // 6 * 128*128 bf16
    int* col    = (int*)(wT + 6 * CC * CC);           // EE
    int* rowptr    = col + EE;                        // NN+1
    int* deg       = rowptr + NN + 1;                 // NN
    int* blockSums = deg + NN;                        // NB_SCAN
    int* blockOff  = blockSums + NB_SCAN;             // NB_SCAN

    // rank[] (EE ints = 6.4 MB) aliases agg (25.6 MB): dead until first gather
    int* rank = (int*)agg;

    ushort* w0aT = wT;
    ushort* w0bT = wT + 1 * CC * CC;
    ushort* w1aT = wT + 2 * CC * CC;
    ushort* w1bT = wT + 3 * CC * CC;
    ushort* w2aT = wT + 4 * CC * CC;
    ushort* w2bT = wT + 5 * CC * CC;

    const int gatherBlocks = NN / 16;                 // 6250
    const int cvtXBlocks   = (NN * CC / 4) / 256;     // 12500

    // ---- conversions (convert_x also zeroes deg) ----
    convert_x_kernel<<<cvtXBlocks, 256, 0, stream>>>(x, xb, deg);
    convert_w6_kernel<<<6 * 64, 256, 0, stream>>>(w0a, w0b, w1a, w1b, w2a, w2b, wT);

    // ---- CSR build (rank captured in hist; fill is atomic-free) ----
    hist_part<<<NCHUNKS * NRANGE, 256, 0, stream>>>(dst, deg, rank);
    deg_block_reduce<<<NB_SCAN, 256, 0, stream>>>(deg, blockSums);
    scan_offsets<<<1, 64, 0, stream>>>(blockSums, blockOff, rowptr);
    deg_scan_write<<<NB_SCAN, 256, 0, stream>>>(deg, blockOff, rowptr);
    fill_csr_rank<<<NCHUNKS, 256, 0, stream>>>(src, dst, rank, rowptr, col);

    // ---- layer 1 ----
    gather_agg<<<gatherBlocks, 256, 0, stream>>>(xb, rowptr, col, agg);
    mlp_persist<false><<<MLPB, 512, 0, stream>>>(agg, w0aT, b0a, w0bT, b0b, hbA,
                                                 nullptr, nullptr, nullptr);
    // ---- layer 2 (output into xb) ----
    gather_agg<<<gatherBlocks, 256, 0, stream>>>(hbA, rowptr, col, agg);
    mlp_persist<false><<<MLPB, 512, 0, stream>>>(agg, w1aT, b1a, w1bT, b1b, xb,
                                                 nullptr, nullptr, nullptr);
    // ---- layer 3 + fused head ----
    gather_agg<<<gatherBlocks, 256, 0, stream>>>(xb, rowptr, col, agg);
    mlp_persist<true><<<MLPB, 512, 0, stream>>>(agg, w2aT, b2a, w2bT, b2b, nullptr,
                                                lw, lb, outp);
}

// Round 2
// 449.791 us; speedup vs baseline: 1.2094x; 1.1564x over previous
//
#include <hip/hip_runtime.h>
#include <hip/hip_bf16.h>
#include <math.h>

#define NN 100000
#define CC 128
#define EE 1600000
#define EPT 8                    // edges per thread in edge-chunk kernels
#define FCHUNK (256 * EPT)       // 2048 edges per block
#define NCHUNKS ((EE + FCHUNK - 1) / FCHUNK)  // 782
#define NB_E NCHUNKS             // edge chunks
#define WB 512                   // nodes per bucket (power of 2)
#define WSHIFT 9
#define NBUCK ((NN + WB - 1) / WB)  // 196

typedef short  bf16x8 __attribute__((ext_vector_type(8)));
typedef float  f32x4  __attribute__((ext_vector_type(4)));
typedef float  f32x4v __attribute__((ext_vector_type(4)));
typedef unsigned short u16x8 __attribute__((ext_vector_type(8)));

#define WPAD 136   // ushort stride for LDS weight rows (272 B -> 2-way bank alias, free)
#define TPAD 132   // float stride for per-wave T tiles (528 B)
#define MLPB 256   // persistent MLP blocks (1 per CU)
#define MLPW 8     // waves per MLP block (512 thr): 2 waves/SIMD at 1 block/CU

__device__ __forceinline__ ushort f2bf(float f) {
    __hip_bfloat16 h = __float2bfloat16(f);   // RNE
    return __builtin_bit_cast(ushort, h);
}
__device__ __forceinline__ float bf2f(ushort u) {
    return __builtin_bit_cast(float, ((unsigned int)u) << 16);
}

// ===========================================================================
// CSR build via bucketed counting sort — ZERO global atomics.
// Old path (hist 73.6us + fill ~55us) was bound by 1.6M global atomic chains
// (~21G/s fabric floor) and 1.6M scattered 4B col stores (~100MB line RFO).
// New path keeps all fine-grained ops in LDS; global traffic is streamed.
//   bucket k = dst >> 9 (512 nodes/bucket, 196 buckets)
//   pairs[e] packed u32 = (src << 9) | (dst & 511)   (17+9 = 26 bits)
// ===========================================================================

// Pass 1a: per-chunk LDS histogram of buckets -> cnt[bucket][chunk]
__global__ void __launch_bounds__(256) bucket_hist(
    const int* __restrict__ dst, int* __restrict__ cnt)
{
    __shared__ int h[NBUCK];
    for (int i = threadIdx.x; i < NBUCK; i += 256) h[i] = 0;
    __syncthreads();
    int base = blockIdx.x * FCHUNK + threadIdx.x * EPT;
    if (base + EPT <= EE) {
        int4 d0 = *(const int4*)&dst[base];
        int4 d1 = *(const int4*)&dst[base + 4];
        int dd[8] = {d0.x, d0.y, d0.z, d0.w, d1.x, d1.y, d1.z, d1.w};
#pragma unroll
        for (int i = 0; i < 8; ++i) atomicAdd(&h[dd[i] >> WSHIFT], 1);
    } else {
        for (int i = 0; i < EPT; ++i) {
            int e = base + i;
            if (e < EE) atomicAdd(&h[dst[e] >> WSHIFT], 1);
        }
    }
    __syncthreads();
    for (int i = threadIdx.x; i < NBUCK; i += 256)
        cnt[i * NB_E + blockIdx.x] = h[i];
}

// Pass 1b-i: per-bucket exclusive scan over the 782 chunk counts (in place),
// bucket totals out.
__global__ void __launch_bounds__(256) scan_cnt(
    int* __restrict__ cnt, int* __restrict__ total)
{
    __shared__ int wsum[4];
    int row = blockIdx.x;
    int* p = cnt + row * NB_E;
    int tid = threadIdx.x, lane = tid & 63, wid = tid >> 6;
    int v[4], s = 0;
#pragma unroll
    for (int j = 0; j < 4; ++j) {
        int idx = tid * 4 + j;
        v[j] = (idx < NB_E) ? p[idx] : 0;
        s += v[j];
    }
    int inc = s;
#pragma unroll
    for (int off = 1; off < 64; off <<= 1) {
        int n = __shfl_up(inc, off);
        if (lane >= off) inc += n;
    }
    if (lane == 63) wsum[wid] = inc;
    __syncthreads();
    int wofs = 0;
#pragma unroll
    for (int w = 0; w < 4; ++w)
        if (w < wid) wofs += wsum[w];
    int run = wofs + inc - s;   // exclusive prefix for this thread's 4 values
#pragma unroll
    for (int j = 0; j < 4; ++j) {
        int idx = tid * 4 + j;
        if (idx < NB_E) p[idx] = run;
        run += v[j];
    }
    if (tid == 255) total[row] = run;   // grand total (tail v[] are 0)
}

// Pass 1b-ii: scan 196 bucket totals -> bucketBase; also terminators.
__global__ void scan_base(const int* __restrict__ total,
                          int* __restrict__ bucketBase, int* __restrict__ rowptr)
{
    int lane = threadIdx.x;   // 64 threads
    int v[4], s = 0;
#pragma unroll
    for (int j = 0; j < 4; ++j) {
        int idx = lane * 4 + j;
        v[j] = (idx < NBUCK) ? total[idx] : 0;
        s += v[j];
    }
    int inc = s;
#pragma unroll
    for (int off = 1; off < 64; off <<= 1) {
        int n = __shfl_up(inc, off);
        if (lane >= off) inc += n;
    }
    int run = inc - s;
#pragma unroll
    for (int j = 0; j < 4; ++j) {
        int idx = lane * 4 + j;
        if (idx < NBUCK) bucketBase[idx] = run;
        run += v[j];
    }
    if (lane == 63) { bucketBase[NBUCK] = EE; rowptr[NN] = EE; }
}

// Pass 1c: scatter packed pairs into per-(chunk,bucket) reserved runs.
// Ranks via LDS atomics; stores land in ~10-edge (~40-80B) coalesced runs.
__global__ void __launch_bounds__(256) bucket_scatter(
    const int* __restrict__ src, const int* __restrict__ dst,
    const int* __restrict__ cntEx, const int* __restrict__ bucketBase,
    unsigned int* __restrict__ pairs)
{
    __shared__ int h[NBUCK];
    __shared__ int bOfs[NBUCK];
    for (int i = threadIdx.x; i < NBUCK; i += 256) {
        h[i] = 0;
        bOfs[i] = bucketBase[i] + cntEx[i * NB_E + blockIdx.x];
    }
    __syncthreads();
    int base = blockIdx.x * FCHUNK + threadIdx.x * EPT;
    if (base + EPT <= EE) {
        int4 d0 = *(const int4*)&dst[base];
        int4 d1 = *(const int4*)&dst[base + 4];
        int4 s0 = *(const int4*)&src[base];
        int4 s1 = *(const int4*)&src[base + 4];
        int dd[8] = {d0.x, d0.y, d0.z, d0.w, d1.x, d1.y, d1.z, d1.w};
        int ss[8] = {s0.x, s0.y, s0.z, s0.w, s1.x, s1.y, s1.z, s1.w};
#pragma unroll
        for (int i = 0; i < 8; ++i) {
            int d = dd[i];
            int k = d >> WSHIFT;
            int r = atomicAdd(&h[k], 1);
            pairs[bOfs[k] + r] = ((unsigned)ss[i] << WSHIFT) | (unsigned)(d & (WB - 1));
        }
    } else {
        for (int i = 0; i < EPT; ++i) {
            int e = base + i;
            if (e < EE) {
                int d = dst[e];
                int k = d >> WSHIFT;
                int r = atomicAdd(&h[k], 1);
                pairs[bOfs[k] + r] = ((unsigned)src[e] << WSHIFT) | (unsigned)(d & (WB - 1));
            }
        }
    }
}

// Pass 2: per bucket — LDS node hist -> LDS scan -> rowptr, then LDS-rank
// scatter of col into the bucket's contiguous window (L2-local).
__global__ void __launch_bounds__(256) csr_build(
    const unsigned int* __restrict__ pairs, const int* __restrict__ bucketBase,
    int* __restrict__ rowptr, int* __restrict__ col)
{
    __shared__ int cnt[WB];
    __shared__ int ofs[WB];
    __shared__ int wsum[4];
    int k = blockIdx.x;
    int tid = threadIdx.x, lane = tid & 63, wid = tid >> 6;
    int nodeBase = k * WB;
    int nNodes = NN - nodeBase; if (nNodes > WB) nNodes = WB;
    for (int i = tid; i < WB; i += 256) cnt[i] = 0;
    __syncthreads();
    int beg = bucketBase[k], end = bucketBase[k + 1];
    for (int e = beg + tid; e < end; e += 256)
        atomicAdd(&cnt[pairs[e] & (WB - 1)], 1);
    __syncthreads();
    // exclusive scan of cnt[512] (2 values per thread)
    int a = cnt[2 * tid], b = cnt[2 * tid + 1];
    int s = a + b;
    int inc = s;
#pragma unroll
    for (int off = 1; off < 64; off <<= 1) {
        int n = __shfl_up(inc, off);
        if (lane >= off) inc += n;
    }
    if (lane == 63) wsum[wid] = inc;
    __syncthreads();
    int wofs = 0;
#pragma unroll
    for (int w = 0; w < 4; ++w)
        if (w < wid) wofs += wsum[w];
    int excl = wofs + inc - s;
    ofs[2 * tid] = excl;
    ofs[2 * tid + 1] = excl + a;
    __syncthreads();
    for (int i = tid; i < nNodes; i += 256)
        rowptr[nodeBase + i] = beg + ofs[i];
    __syncthreads();   // rowptr reads of ofs[] complete before cursor mutation
    for (int e = beg + tid; e < end; e += 256) {
        unsigned p = pairs[e];
        int dl = p & (WB - 1);
        int r = atomicAdd(&ofs[dl], 1);
        col[beg + r] = (int)(p >> WSHIFT);
    }
}

// ===========================================================================
// Conversions
// ===========================================================================
__global__ void __launch_bounds__(256) convert_x_kernel(
    const float* __restrict__ x, ushort* __restrict__ xb)
{
    int i = blockIdx.x * 256 + threadIdx.x;   // float4 groups; NN*CC/4 total
    f32x4v v = __builtin_nontemporal_load((const f32x4v*)x + i);  // single-use stream
    ushort4 o;
    o.x = f2bf(v[0]); o.y = f2bf(v[1]); o.z = f2bf(v[2]); o.w = f2bf(v[3]);
    ((ushort4*)xb)[i] = o;
}

__global__ void __launch_bounds__(256) convert_w6_kernel(
    const float* __restrict__ w0, const float* __restrict__ w1,
    const float* __restrict__ w2, const float* __restrict__ w3,
    const float* __restrict__ w4, const float* __restrict__ w5,
    ushort* __restrict__ wt)
{
    int i = blockIdx.x * 256 + threadIdx.x;  // 6*16384
    int mat = i >> 14;
    int rem = i & 16383;
    int k = rem >> 7, n = rem & 127;
    const float* w = (mat == 0) ? w0 : (mat == 1) ? w1 : (mat == 2) ? w2
                   : (mat == 3) ? w3 : (mat == 4) ? w4 : w5;
    wt[mat * 16384 + n * 128 + k] = f2bf(w[k * 128 + n]);
}

// ===========================================================================
// Standalone max-occupancy gather: agg[n] = h[n] + sum_nbr h[nbr]  (bf16)
// At the random-graph L2-miss floor (~67 us/layer).
// ===========================================================================
__global__ void __launch_bounds__(256) gather_agg(
    const ushort* __restrict__ hin, const int* __restrict__ rowptr,
    const int* __restrict__ col, ushort* __restrict__ agg)
{
    const int grp    = threadIdx.x >> 4;            // 0..15
    const int lane16 = threadIdx.x & 15;
    const int gbase  = (threadIdx.x & 63) & 48;     // group base lane in wave
    const int n = blockIdx.x * 16 + grp;            // 6250*16 = 100000 exact
    const u16x8* hp = (const u16x8*)hin;

    u16x8 self = hp[n * 16 + lane16];
    float s0[8], s1[8], s2[8], s3[8];
#pragma unroll
    for (int k = 0; k < 8; ++k) {
        s0[k] = bf2f(self[k]); s1[k] = 0.f; s2[k] = 0.f; s3[k] = 0.f;
    }

    int beg = rowptr[n], end = rowptr[n + 1];
    while (beg < end) {
        int take = end - beg;
        if (take > 16) take = 16;
        int ci = (lane16 < take) ? col[beg + lane16] : 0;
        int j = 0;
        for (; j + 4 <= take; j += 4) {
            int n0 = __shfl(ci, gbase + j + 0);
            int n1 = __shfl(ci, gbase + j + 1);
            int n2 = __shfl(ci, gbase + j + 2);
            int n3 = __shfl(ci, gbase + j + 3);
            u16x8 a0 = hp[n0 * 16 + lane16];
            u16x8 a1 = hp[n1 * 16 + lane16];
            u16x8 a2 = hp[n2 * 16 + lane16];
            u16x8 a3 = hp[n3 * 16 + lane16];
#pragma unroll
            for (int k = 0; k < 8; ++k) {
                s0[k] += bf2f(a0[k]); s1[k] += bf2f(a1[k]);
                s2[k] += bf2f(a2[k]); s3[k] += bf2f(a3[k]);
            }
        }
        for (; j < take; ++j) {
            int n0 = __shfl(ci, gbase + j);
            u16x8 a0 = hp[n0 * 16 + lane16];
#pragma unroll
            for (int k = 0; k < 8; ++k) s0[k] += bf2f(a0[k]);
        }
        beg += take;
    }

    bf16x8 o;
#pragma unroll
    for (int k = 0; k < 8; ++k) o[k] = (short)f2bf(s0[k] + s1[k] + s2[k] + s3[k]);
    *(bf16x8*)&((ushort*)agg)[n * CC + lane16 * 8] = o;
}

// ===========================================================================
// Persistent weights-in-LDS MFMA MLP: 256 blocks (1/CU), 8 waves/block
// (512 thr) -> 2 waves/SIMD. LDS: 2*34816 (weights) + 8*8448 (T) = 137216 B.
// ===========================================================================
template <bool FUSE_HEAD>
__global__ void __launch_bounds__(512, 2) mlp_persist(
    const ushort* __restrict__ hin,
    const ushort* __restrict__ waT, const float* __restrict__ ba,
    const ushort* __restrict__ wbT, const float* __restrict__ bb,
    ushort* __restrict__ hout,
    const float* __restrict__ lw, const float* __restrict__ lb,
    float* __restrict__ out)
{
    __shared__ ushort WaS[CC * WPAD];      // [n][k], row stride 136
    __shared__ ushort WbS[CC * WPAD];
    __shared__ float  Tt[MLPW][16 * TPAD]; // per-wave private T

    const int tid = threadIdx.x;

    // ---- cooperative weight staging (coalesced 16B chunks) ----
    for (int i = tid; i < CC * 16; i += 512) {         // 2048 chunks per matrix
        int row = i >> 4, ch = i & 15;
        *(bf16x8*)&WaS[row * WPAD + ch * 8] = *(const bf16x8*)&waT[row * CC + ch * 8];
        *(bf16x8*)&WbS[row * WPAD + ch * 8] = *(const bf16x8*)&wbT[row * CC + ch * 8];
    }
    __syncthreads();

    const int wave = tid >> 6;
    const int lane = tid & 63;
    const int quad = lane >> 4;
    const int l16  = lane & 15;
    float* T = Tt[wave];
    const int nTiles = NN / 16;            // 6250
    const int stride = MLPB * MLPW;        // 2048

    int wv = blockIdx.x * MLPW + wave;
    if (wv >= nTiles) return;

    // prefetch first tile's A fragments
    bf16x8 af[4];
#pragma unroll
    for (int kk = 0; kk < 4; ++kk)
        af[kk] = *(const bf16x8*)&hin[(wv * 16 + l16) * CC + kk * 32 + quad * 8];

    while (true) {
        const int wrow0 = wv * 16;
        const int wnext = wv + stride;

        // prefetch next tile's A fragments (independent of current compute)
        bf16x8 afn[4];
        if (wnext < nTiles) {
#pragma unroll
            for (int kk = 0; kk < 4; ++kk)
                afn[kk] = *(const bf16x8*)&hin[(wnext * 16 + l16) * CC + kk * 32 + quad * 8];
        }

        // ---- stage 1: T = relu(A @ Wa + ba), B from LDS ----
        f32x4 acc[8];
#pragma unroll
        for (int nt = 0; nt < 8; ++nt) acc[nt] = (f32x4){0.f, 0.f, 0.f, 0.f};
#pragma unroll
        for (int kk = 0; kk < 4; ++kk) {
#pragma unroll
            for (int nt = 0; nt < 8; ++nt) {
                bf16x8 bfrag = *(const bf16x8*)&WaS[(nt * 16 + l16) * WPAD + kk * 32 + quad * 8];
                acc[nt] = __builtin_amdgcn_mfma_f32_16x16x32_bf16(af[kk], bfrag, acc[nt], 0, 0, 0);
            }
        }
#pragma unroll
        for (int nt = 0; nt < 8; ++nt) {
            int colc = nt * 16 + l16;
            float bias = ba[colc];
#pragma unroll
            for (int r = 0; r < 4; ++r) {
                float v = acc[nt][r] + bias;
                T[(quad * 4 + r) * TPAD + colc] = fmaxf(v, 0.f);
            }
        }
        // within-wave LDS write->read: compiler lgkmcnt, no barrier

        // ---- stage-2 A fragments from T (cvt fp32 -> bf16) ----
        bf16x8 a2[4];
#pragma unroll
        for (int kk = 0; kk < 4; ++kk) {
            const float* tp = &T[l16 * TPAD + kk * 32 + quad * 8];
            float4 t0 = *(const float4*)tp;
            float4 t1 = *(const float4*)(tp + 4);
            bf16x8 f;
            f[0] = (short)f2bf(t0.x); f[1] = (short)f2bf(t0.y);
            f[2] = (short)f2bf(t0.z); f[3] = (short)f2bf(t0.w);
            f[4] = (short)f2bf(t1.x); f[5] = (short)f2bf(t1.y);
            f[6] = (short)f2bf(t1.z); f[7] = (short)f2bf(t1.w);
            a2[kk] = f;
        }

        // ---- stage 2: out = elu(T @ Wb + bb), B from LDS ----
        f32x4 acc2[8];
#pragma unroll
        for (int nt = 0; nt < 8; ++nt) acc2[nt] = (f32x4){0.f, 0.f, 0.f, 0.f};
#pragma unroll
        for (int kk = 0; kk < 4; ++kk) {
#pragma unroll
            for (int nt = 0; nt < 8; ++nt) {
                bf16x8 bfrag = *(const bf16x8*)&WbS[(nt * 16 + l16) * WPAD + kk * 32 + quad * 8];
                acc2[nt] = __builtin_amdgcn_mfma_f32_16x16x32_bf16(a2[kk], bfrag, acc2[nt], 0, 0, 0);
            }
        }

        if (FUSE_HEAD) {
            float part[4] = {0.f, 0.f, 0.f, 0.f};
#pragma unroll
            for (int nt = 0; nt < 8; ++nt) {
                int colc = nt * 16 + l16;
                float bias = bb[colc];
                float w = lw[colc];
#pragma unroll
                for (int r = 0; r < 4; ++r) {
                    float v = acc2[nt][r] + bias;
                    v = v > 0.f ? v : expm1f(v);
                    part[r] += v * w;
                }
            }
#pragma unroll
            for (int r = 0; r < 4; ++r) {
#pragma unroll
                for (int off = 8; off > 0; off >>= 1)
                    part[r] += __shfl_xor(part[r], off);
            }
            if (l16 == 0) {
                float lbv = lb[0];
#pragma unroll
                for (int r = 0; r < 4; ++r) {
                    int grow = wrow0 + quad * 4 + r;
                    float z = part[r] + lbv;
                    out[grow] = 1.f / (1.f + expf(-z));
                }
            }
        } else {
            // elu -> T (safe: same-wave a2 reads returned) -> coalesced bf16 store
#pragma unroll
            for (int nt = 0; nt < 8; ++nt) {
                int colc = nt * 16 + l16;
                float bias = bb[colc];
#pragma unroll
                for (int r = 0; r < 4; ++r) {
                    float v = acc2[nt][r] + bias;
                    T[(quad * 4 + r) * TPAD + colc] = v > 0.f ? v : expm1f(v);
                }
            }
#pragma unroll
            for (int i = 0; i < 4; ++i) {
                int r  = i * 4 + quad;           // 0..15
                int cv = l16;                    // 16B chunk (8 values)
                const float* tp = &T[r * TPAD + cv * 8];
                float4 t0 = *(const float4*)tp;
                float4 t1 = *(const float4*)(tp + 4);
                ushort4 o0, o1;
                o0.x = f2bf(t0.x); o0.y = f2bf(t0.y); o0.z = f2bf(t0.z); o0.w = f2bf(t0.w);
                o1.x = f2bf(t1.x); o1.y = f2bf(t1.y); o1.z = f2bf(t1.z); o1.w = f2bf(t1.w);
                ushort* dstp = &hout[(wrow0 + r) * CC + cv * 8];
                *(ushort4*)dstp = o0;
                *(ushort4*)(dstp + 4) = o1;
            }
        }

        if (wnext >= nTiles) break;
        wv = wnext;
#pragma unroll
        for (int kk = 0; kk < 4; ++kk) af[kk] = afn[kk];
    }
}

extern "C" void kernel_launch(void* const* d_in, const int* in_sizes, int n_in,
                              void* d_out, int out_size, void* d_ws, size_t ws_size,
                              hipStream_t stream) {
    const float* x   = (const float*)d_in[0];
    const int*   ei  = (const int*)d_in[1];
    const int*   src = ei;
    const int*   dst = ei + EE;
    const float* w0a = (const float*)d_in[2];
    const float* b0a = (const float*)d_in[3];
    const float* w0b = (const float*)d_in[4];
    const float* b0b = (const float*)d_in[5];
    const float* w1a = (const float*)d_in[6];
    const float* b1a = (const float*)d_in[7];
    const float* w1b = (const float*)d_in[8];
    const float* b1b = (const float*)d_in[9];
    const float* w2a = (const float*)d_in[10];
    const float* b2a = (const float*)d_in[11];
    const float* w2b = (const float*)d_in[12];
    const float* b2b = (const float*)d_in[13];
    const float* lw  = (const float*)d_in[14];
    const float* lb  = (const float*)d_in[15];
    float* outp = (float*)d_out;

    // workspace layout (xb reused as layer-2 output)
    ushort* xb  = (ushort*)d_ws;                      // N*CC bf16
    ushort* hbA = xb + (size_t)NN * CC;               // N*CC bf16
    ushort* agg = hbA + (size_t)NN * CC;              // N*CC bf16
    ushort* wT  = agg + (size_t)NN * CC;              // 6 * 128*128 bf16
    int* col    = (int*)(wT + 6 * CC * CC);           // EE
    int* rowptr = col + EE;                           // NN+1

    // CSR-build temporaries alias agg (dead until the first gather):
    //   pairs: EE u32 (6.4 MB); cnt: NBUCK*NB_E (613 KB); total/base: tiny
    unsigned int* pairs = (unsigned int*)agg;
    int* cnt        = (int*)(pairs + EE);
    int* total      = cnt + NBUCK * NB_E;
    int* bucketBase = total + NBUCK;                  // NBUCK+1

    ushort* w0aT = wT;
    ushort* w0bT = wT + 1 * CC * CC;
    ushort* w1aT = wT + 2 * CC * CC;
    ushort* w1bT = wT + 3 * CC * CC;
    ushort* w2aT = wT + 4 * CC * CC;
    ushort* w2bT = wT + 5 * CC * CC;

    const int gatherBlocks = NN / 16;                 // 6250
    const int cvtXBlocks   = (NN * CC / 4) / 256;     // 12500

    // ---- conversions ----
    convert_x_kernel<<<cvtXBlocks, 256, 0, stream>>>(x, xb);
    convert_w6_kernel<<<6 * 64, 256, 0, stream>>>(w0a, w0b, w1a, w1b, w2a, w2b, wT);

    // ---- CSR build (bucketed counting sort, no global atomics) ----
    bucket_hist<<<NB_E, 256, 0, stream>>>(dst, cnt);
    scan_cnt<<<NBUCK, 256, 0, stream>>>(cnt, total);
    scan_base<<<1, 64, 0, stream>>>(total, bucketBase, rowptr);
    bucket_scatter<<<NB_E, 256, 0, stream>>>(src, dst, cnt, bucketBase, pairs);
    csr_build<<<NBUCK, 256, 0, stream>>>(pairs, bucketBase, rowptr, col);

    // ---- layer 1 ----
    gather_agg<<<gatherBlocks, 256, 0, stream>>>(xb, rowptr, col, agg);
    mlp_persist<false><<<MLPB, 512, 0, stream>>>(agg, w0aT, b0a, w0bT, b0b, hbA,
                                                 nullptr, nullptr, nullptr);
    // ---- layer 2 (output into xb) ----
    gather_agg<<<gatherBlocks, 256, 0, stream>>>(hbA, rowptr, col, agg);
    mlp_persist<false><<<MLPB, 512, 0, stream>>>(agg, w1aT, b1a, w1bT, b1b, xb,
                                                 nullptr, nullptr, nullptr);
    // ---- layer 3 + fused head ----
    gather_agg<<<gatherBlocks, 256, 0, stream>>>(xb, rowptr, col, agg);
    mlp_persist<true><<<MLPB, 512, 0, stream>>>(agg, w2aT, b2a, w2bT, b2b, nullptr,
                                                lw, lb, outp);
}